// Round 7
// baseline (178.270 us; speedup 1.0000x reference)
//
#include <hip/hip_runtime.h>

// Graph transformer conv on MI355X. N=100000, E=1.6M, DIM=64, H=4, D=8.
// Round 7: concurrency fixes for the gather phase. 512-thread sort_aggregate
// blocks (4/CU resident instead of 1), explicit double-buffered 4-wide gather
// pipeline (forces loads in flight), byte offsets precomputed in LDS sort.

#define NDIM 64
#define NBMAX 1024      // buckets of 128 nodes
#define CTILE 8192
#define STGMAX 4352     // per-bucket edge capacity (mean 2048, sd ~45)

static __device__ __forceinline__ unsigned short f2bf(float f) {
    unsigned int u = __float_as_uint(f);
    unsigned int r = (u + 0x7fffu + ((u >> 16) & 1u)) >> 16;  // RNE
    return (unsigned short)r;
}

// ---- 1. count edges per 128-node bucket --------------------------------
__global__ void bucket_count_kernel(const int* __restrict__ s_arr,
                                    unsigned int* __restrict__ bcnt, int E) {
    __shared__ unsigned int h[NBMAX];
    for (int i = threadIdx.x; i < NBMAX; i += blockDim.x) h[i] = 0;
    __syncthreads();
    int i0 = blockIdx.x * blockDim.x + threadIdx.x;
    int st = gridDim.x * blockDim.x;
    for (int e = i0; e < E; e += st)
        atomicAdd(&h[(unsigned)s_arr[e] >> 7], 1u);
    __syncthreads();
    for (int i = threadIdx.x; i < NBMAX; i += blockDim.x)
        if (h[i]) atomicAdd(&bcnt[i], h[i]);
}

// ---- 2. exclusive scan of bucket counts --------------------------------
__global__ void scan_buckets_kernel(const unsigned int* __restrict__ bcnt,
                                    unsigned int* __restrict__ bbase,
                                    unsigned int* __restrict__ gcur) {
    __shared__ unsigned int sh[1024];
    int tid = threadIdx.x;
    unsigned int v = bcnt[tid];
    unsigned int acc = v;
    sh[tid] = acc;
    __syncthreads();
    for (int off = 1; off < 1024; off <<= 1) {
        unsigned int add = (tid >= off) ? sh[tid - off] : 0;
        __syncthreads();
        acc += add;
        sh[tid] = acc;
        __syncthreads();
    }
    bbase[tid] = acc - v;
    gcur[tid]  = acc - v;
}

// ---- 3. bin edges into bucket-major order, chunk-coalesced -------------
__global__ void __launch_bounds__(1024, 2)
bin_kernel(const int* __restrict__ s_arr,
           const int* __restrict__ t_arr,
           unsigned int* __restrict__ gcur,
           unsigned int* __restrict__ binned, int E) {
    __shared__ unsigned int hist[NBMAX];
    __shared__ unsigned int off[NBMAX];
    __shared__ unsigned int gbase[NBMAX];
    __shared__ unsigned int stg[CTILE];
    __shared__ unsigned int psum[NBMAX];
    int tid = threadIdx.x;
    int e0 = blockIdx.x * CTILE;
    int cnt = min(CTILE, E - e0);

    hist[tid] = 0;
    __syncthreads();
    for (int i = tid; i < cnt; i += 1024)
        atomicAdd(&hist[(unsigned)s_arr[e0 + i] >> 7], 1u);
    __syncthreads();

    unsigned int v = hist[tid];
    unsigned int acc = v;
    psum[tid] = acc;
    __syncthreads();
    for (int o = 1; o < 1024; o <<= 1) {
        unsigned int add = (tid >= o) ? psum[tid - o] : 0;
        __syncthreads();
        acc += add;
        psum[tid] = acc;
        __syncthreads();
    }
    off[tid] = acc - v;
    __syncthreads();

    for (int i = tid; i < cnt; i += 1024) {
        int s = s_arr[e0 + i];
        int t = t_arr[e0 + i];
        unsigned int bkt = (unsigned)s >> 7;
        unsigned int p = atomicAdd(&off[bkt], 1u);
        stg[p] = ((unsigned)(s & 127) << 17) | (unsigned)t;
    }
    __syncthreads();

    {
        unsigned int h = hist[tid];
        gbase[tid] = h ? atomicAdd(&gcur[tid], h) : 0u;
    }
    __syncthreads();

    int wid = tid >> 6, lane = tid & 63;
    for (int b = wid; b < NBMAX; b += 16) {
        unsigned int h = hist[b];
        if (h == 0) continue;
        unsigned int src = off[b] - h;
        unsigned int dst = gbase[b];
        for (unsigned int i = lane; i < h; i += 64)
            binned[dst + i] = stg[src + i];
    }
}

// ---- 4. qkv GEMM: W in regs, x broadcast from LDS, 8 rows per barrier ---
__global__ void qkv_gemm_kernel(const float* __restrict__ x,
                                const float* __restrict__ W,
                                const float* __restrict__ b,
                                float* __restrict__ qs,
                                unsigned short* __restrict__ kv, int N) {
    int col = threadIdx.x & 127;
    int rw  = threadIdx.x >> 7;
    float w[64];
    #pragma unroll
    for (int k = 0; k < 64; ++k) w[k] = W[k * 128 + col];
    float bias = b[col];
    __shared__ float4 xs[8][16];

    for (int r0 = blockIdx.x * 8; r0 < N; r0 += gridDim.x * 8) {
        __syncthreads();
        if (threadIdx.x < 128) {
            int rr = threadIdx.x >> 4;
            int cc = threadIdx.x & 15;
            int n = r0 + rr;
            xs[rr][cc] = (n < N)
                ? reinterpret_cast<const float4*>(x)[(size_t)n * 16 + cc]
                : make_float4(0.f, 0.f, 0.f, 0.f);
        }
        __syncthreads();
        #pragma unroll
        for (int rsub = 0; rsub < 4; ++rsub) {
            int rr = rw * 4 + rsub;
            int n = r0 + rr;
            if (n < N) {
                float acc = bias;
                #pragma unroll
                for (int k4 = 0; k4 < 16; ++k4) {
                    float4 xv = xs[rr][k4];
                    acc = fmaf(xv.x, w[4 * k4 + 0], acc);
                    acc = fmaf(xv.y, w[4 * k4 + 1], acc);
                    acc = fmaf(xv.z, w[4 * k4 + 2], acc);
                    acc = fmaf(xv.w, w[4 * k4 + 3], acc);
                }
                if (col < 32) {
                    qs[(size_t)n * 32 + col] = acc;
                } else if (col < 64) {
                    kv[(size_t)n * 96 + (col - 32)] = f2bf(acc);
                } else {
                    kv[(size_t)n * 96 + 32 + (col - 64)] = f2bf(acc);
                }
            }
        }
    }
}

// ---- 5. fused per-bucket sort + aggregate ------------------------------
// 512 threads (8 waves) per 128-node bucket; wave w -> local nodes
// [16w, 16w+16). LDS sort stores BYTE offsets (t*192). Edge loop is an
// explicit double-buffered 4-wide pipeline: next-4 gathers issued before
// computing current-4, so 4-8 loads stay in flight per wave.
#define COMPUTE_EDGE(rr)                                              \
    {                                                                 \
        float lo = __uint_as_float((rr) << 16);                       \
        float hi = __uint_as_float((rr) & 0xffff0000u);               \
        float p = fmaf(q0, lo, q1 * hi);                              \
        p += __shfl_xor(p, 1);                                        \
        p += __shfl_xor(p, 2);                                        \
        float c = __shfl(p, csrc);                                    \
        float w = __expf(c);                                          \
        accx = fmaf(w, lo, accx);                                     \
        accy = fmaf(w, hi, accy);                                     \
        den += w;                                                     \
    }

__global__ void __launch_bounds__(512, 8)
sort_aggregate_kernel(const unsigned int* __restrict__ bbase,
                      const unsigned int* __restrict__ bcnt,
                      const unsigned int* __restrict__ binned,
                      const float* __restrict__ qs,
                      const unsigned int* __restrict__ kv32,
                      float* __restrict__ out, int N) {
    __shared__ unsigned int hist[128];
    __shared__ unsigned int rstart[128];
    __shared__ unsigned int cur[128];
    __shared__ unsigned int sh[128];
    __shared__ unsigned int stg[STGMAX];

    int b = blockIdx.x;
    int tid = threadIdx.x;
    unsigned int base = bbase[b];
    unsigned int cnt = min(bcnt[b], (unsigned int)STGMAX);

    if (tid < 128) hist[tid] = 0;
    __syncthreads();
    for (unsigned int i = tid; i < cnt; i += 512)
        atomicAdd(&hist[binned[base + i] >> 17], 1u);
    __syncthreads();

    unsigned int v = (tid < 128) ? hist[tid] : 0;
    unsigned int acc = v;
    if (tid < 128) sh[tid] = acc;
    __syncthreads();
    for (int o = 1; o < 128; o <<= 1) {
        unsigned int add = (tid >= o && tid < 128) ? sh[tid - o] : 0;
        __syncthreads();
        if (tid < 128) { acc += add; sh[tid] = acc; }
        __syncthreads();
    }
    if (tid < 128) {
        unsigned int exc = acc - v;
        rstart[tid] = exc;
        cur[tid] = exc;
    }
    __syncthreads();

    for (unsigned int i = tid; i < cnt; i += 512) {
        unsigned int e = binned[base + i];
        unsigned int p = atomicAdd(&cur[e >> 17], 1u);
        stg[p] = (e & 0x1FFFFu) * 192u;     // byte offset into kv table
    }
    __syncthreads();

    int wid = tid >> 6, lane = tid & 63;
    unsigned int lane4 = ((unsigned int)lane) << 2;
    bool ldact = (lane < 48);
    const char* kvb = (const char*)kv32;
    int csrc = (lane < 16) ? (lane & ~3)
             : (lane < 48) ? (((lane - 16) >> 3) << 2)
                           : 0;

    for (int nl = wid * 16; nl < wid * 16 + 16; ++nl) {
        int n = b * 128 + nl;
        if (n >= N) break;
        int dg = (int)hist[nl];
        if (dg == 0) {
            if (lane >= 16 && lane < 48)
                *reinterpret_cast<float2*>(&out[(size_t)n * 64 + 2 * (lane - 16)]) =
                    make_float2(0.f, 0.f);
            continue;
        }
        int start = (int)rstart[nl];
        float sc = 0.25f * rsqrtf((float)dg);
        float q0 = 0.f, q1 = 0.f;
        if (lane < 16) {
            q0 = qs[(size_t)n * 32 + 2 * lane] * sc;
            q1 = qs[(size_t)n * 32 + 2 * lane + 1] * sc;
        }

        float accx = 0.f, accy = 0.f, den = 0.f;
        int j = start;
        int rem = dg;

        unsigned int ra0 = 0, ra1 = 0, ra2 = 0, ra3 = 0;
        if (rem >= 4) {
            unsigned int o0 = stg[j] + lane4,     o1 = stg[j + 1] + lane4;
            unsigned int o2 = stg[j + 2] + lane4, o3 = stg[j + 3] + lane4;
            if (ldact) {
                ra0 = *(const unsigned int*)(kvb + o0);
                ra1 = *(const unsigned int*)(kvb + o1);
                ra2 = *(const unsigned int*)(kvb + o2);
                ra3 = *(const unsigned int*)(kvb + o3);
            }
        }
        while (rem >= 4) {
            unsigned int rb0 = 0, rb1 = 0, rb2 = 0, rb3 = 0;
            if (rem >= 8) {
                unsigned int o0 = stg[j + 4] + lane4, o1 = stg[j + 5] + lane4;
                unsigned int o2 = stg[j + 6] + lane4, o3 = stg[j + 7] + lane4;
                if (ldact) {
                    rb0 = *(const unsigned int*)(kvb + o0);
                    rb1 = *(const unsigned int*)(kvb + o1);
                    rb2 = *(const unsigned int*)(kvb + o2);
                    rb3 = *(const unsigned int*)(kvb + o3);
                }
            }
            COMPUTE_EDGE(ra0);
            COMPUTE_EDGE(ra1);
            COMPUTE_EDGE(ra2);
            COMPUTE_EDGE(ra3);
            ra0 = rb0; ra1 = rb1; ra2 = rb2; ra3 = rb3;
            j += 4; rem -= 4;
        }
        for (; rem > 0; --rem, ++j) {
            unsigned int o0 = stg[j] + lane4;
            unsigned int r0 = ldact ? *(const unsigned int*)(kvb + o0) : 0u;
            COMPUTE_EDGE(r0);
        }

        if (lane >= 16 && lane < 48) {
            float inv = 1.0f / (den + 1e-16f);
            float2 o = make_float2(accx * inv, accy * inv);
            *reinterpret_cast<float2*>(&out[(size_t)n * 64 + 2 * (lane - 16)]) = o;
        }
    }
}

extern "C" void kernel_launch(void* const* d_in, const int* in_sizes, int n_in,
                              void* d_out, int out_size, void* d_ws, size_t ws_size,
                              hipStream_t stream) {
    const float* x = (const float*)d_in[0];
    const int*   eidx = (const int*)d_in[1];
    const float* W = (const float*)d_in[2];
    const float* b = (const float*)d_in[3];
    int N = in_sizes[0] / NDIM;
    int E = in_sizes[1] / 2;
    float* out = (float*)d_out;

    int NB = (N + 127) / 128;           // 782

    // workspace layout
    float* qs = (float*)d_ws;                                     // N*32 f
    unsigned short* kv = (unsigned short*)(qs + (size_t)N * 32);  // N*96 u16
    unsigned int* bcnt  = (unsigned int*)(kv + (size_t)N * 96);   // NBMAX
    unsigned int* bbase = bcnt + NBMAX;                           // NBMAX
    unsigned int* gcur  = bbase + NBMAX;                          // NBMAX
    unsigned int* binned = gcur + NBMAX;                          // E u32

    const int* s_arr = eidx;
    const int* t_arr = eidx + E;

    hipMemsetAsync(bcnt, 0, NBMAX * sizeof(unsigned int), stream);

    bucket_count_kernel<<<512, 256, 0, stream>>>(s_arr, bcnt, E);
    scan_buckets_kernel<<<1, 1024, 0, stream>>>(bcnt, bbase, gcur);
    bin_kernel<<<(E + CTILE - 1) / CTILE, 1024, 0, stream>>>(s_arr, t_arr, gcur, binned, E);
    qkv_gemm_kernel<<<2048, 256, 0, stream>>>(x, W, b, qs, kv, N);
    sort_aggregate_kernel<<<NB, 512, 0, stream>>>(
        bbase, bcnt, binned, qs, (const unsigned int*)kv, out, N);
}